// Round 7
// baseline (123.802 us; speedup 1.0000x reference)
//
#include <hip/hip_runtime.h>

#define BHH 32      // B*H
#define SEQ 2048
#define DH 64
#define BK 64       // K/V rows per tile
#define NKT (SEQ / BK)   // 32
#define NT  (BHH * NKT)  // 1024 (bh,kt) tiles

typedef __attribute__((ext_vector_type(8))) _Float16 half8_t;
typedef __attribute__((ext_vector_type(4))) _Float16 half4_t;
typedef __attribute__((ext_vector_type(2))) _Float16 half2_t;
typedef __attribute__((ext_vector_type(16))) float f32x16;

__device__ __forceinline__ void async_copy16(const void* g, const void* lds) {
    __builtin_amdgcn_global_load_lds(
        (const __attribute__((address_space(1))) unsigned int*)g,
        (__attribute__((address_space(3))) unsigned int*)lds, 16, 0, 0);
}

__device__ __forceinline__ half2_t pkrtz(float a, float b) {
    return __builtin_bit_cast(half2_t, __builtin_amdgcn_cvt_pkrtz(a, b));
}

__device__ __forceinline__ half8_t cat8(half2_t a, half2_t b, half2_t c, half2_t d) {
    half4_t lo = __builtin_shufflevector(a, b, 0, 1, 2, 3);
    half4_t hi = __builtin_shufflevector(c, d, 0, 1, 2, 3);
    return __builtin_shufflevector(lo, hi, 0, 1, 2, 3, 4, 5, 6, 7);
}

// ---------------------------------------------------------------------------
// Fused prep for the 32x32x16 pipeline. Blocks [0,NT) convert K, [NT,2NT) V.
//   Kf frag = kb*4 + t (kb: 32-row k-block, t: 16-wide dh step):
//     lane L elem j holds K[kb*32 + (L&31)][t*16 + 8*(L>>5) + j]   (QK A-op)
//   Vf frag = dn*4 + b*2 + tt (dn: 32-wide d-block, b: 32-row k-block,
//     tt: k-step within block):
//     lane L elem j holds V[32b + 16tt + (j&3) + 8*(j>>2) + 4*(L>>5)]
//                          [dn*32 + (L&31)]                        (PV A-op)
//   The PV k-permutation matches the 32x32 C/D register order, so the PV
//   B-operand is pkrtz of CONSECUTIVE QK-output registers (zero shuffling).
// ---------------------------------------------------------------------------
__global__ __launch_bounds__(256) void prep_kv(const float* __restrict__ K,
                                               const float* __restrict__ V,
                                               _Float16* __restrict__ Kf,
                                               _Float16* __restrict__ Vf) {
    __shared__ _Float16 l[64 * 76];
    const int t = threadIdx.x;
    const int wave = t >> 6, lane = t & 63, l31 = lane & 31, h = lane >> 5;
    const int row = t >> 2, col0 = (t & 3) * 16;
    int b = blockIdx.x;

    if (b < NT) {                                    // ---- K path ----
        const float4* src = (const float4*)(K + (size_t)b * 4096 + row * 64 + col0);
        #pragma unroll
        for (int q = 0; q < 2; ++q) {
            float4 f0 = src[q * 2], f1 = src[q * 2 + 1];
            half8_t w = { (_Float16)f0.x, (_Float16)f0.y, (_Float16)f0.z, (_Float16)f0.w,
                          (_Float16)f1.x, (_Float16)f1.y, (_Float16)f1.z, (_Float16)f1.w };
            *(half8_t*)&l[row * 72 + col0 + q * 8] = w;
        }
        __syncthreads();
        #pragma unroll
        for (int p = 0; p < 2; ++p) {
            const int frag = wave * 2 + p, kb = frag >> 2, tt = frag & 3;
            half8_t w = *(const half8_t*)&l[(kb * 32 + l31) * 72 + tt * 16 + h * 8];
            *(half8_t*)&Kf[(size_t)b * 4096 + frag * 512 + lane * 8] = w;
        }
    } else {                                         // ---- V path ----
        b -= NT;
        const float4* src = (const float4*)(V + (size_t)b * 4096 + row * 64 + col0);
        #pragma unroll
        for (int q = 0; q < 4; ++q) {
            float4 f = src[q];
            half4_t w = { (_Float16)f.x, (_Float16)f.y, (_Float16)f.z, (_Float16)f.w };
            *(half4_t*)&l[row * 76 + col0 + q * 4] = w;
        }
        __syncthreads();
        #pragma unroll
        for (int p = 0; p < 2; ++p) {
            const int frag = wave * 2 + p, dn = frag >> 2, s = frag & 3;
            const int bb = s >> 1, tt = s & 1;
            half8_t w;
            #pragma unroll
            for (int j = 0; j < 8; ++j) {
                const int krow = bb * 32 + tt * 16 + (j & 3) + (j >> 2) * 8 + h * 4;
                w[j] = l[krow * 76 + dn * 32 + l31];
            }
            *(half8_t*)&Vf[(size_t)b * 4096 + frag * 512 + lane * 8] = w;
        }
    }
}

// ---------------------------------------------------------------------------
// Flash attention, 32x32x16 MFMA: 256 threads = 4 waves; each wave owns 32
// q-rows (one MFMA n-dim). Per 64-k tile: 8 QK + 8 PV MFMAs (HALF the
// instruction count of the 16x16x32 version, the measured limiter).
// Softmax register-resident: lane owns q-row (lane&31); lanes L, L+32 hold
// complementary k-slots -> one shfl_xor(32) for the denominator.
// Grid = 512 blocks, pair-balanced qb order (co-resident pairs = 34 tiles).
// ---------------------------------------------------------------------------
__global__ __launch_bounds__(256, 2) void fattn_kernel(
        const float* __restrict__ Q, const _Float16* __restrict__ Kf,
        const _Float16* __restrict__ Vf, float* __restrict__ O) {
    const int bh = blockIdx.x & 31;
    const int g  = blockIdx.x >> 5;
    const int qb = (g < 8) ? 15 - g : g - 8;         // pairs (15,0),(14,1),...
    const int nkt = 2 * qb + 2;
    const int ktdiag = 2 * qb;
    const int tid  = threadIdx.x;
    const int wave = tid >> 6;
    const int lane = tid & 63;
    const int l31  = lane & 31;
    const int h    = lane >> 5;

    __shared__ _Float16 ldsK[2][4096];               // dbuf 8 KB K-frags
    __shared__ _Float16 ldsV[2][4096];               // dbuf 8 KB V-frags

    const size_t base = (size_t)bh * SEQ * DH;
    const int qrow  = qb * 128 + wave * 32;          // wave's 32 q-rows
    const int q_abs = qrow + l31;                    // lane's q-row
    const size_t tb = (size_t)(bh * NKT) * 4096;

    // Per-wave staging: waves 0,1 copy K halves; waves 2,3 copy V halves.
    const _Float16* gsrc = ((wave < 2) ? Kf : Vf) + tb + (wave & 1) * 2048 + lane * 8;
    _Float16* dst0 = ((wave < 2) ? &ldsK[0][0] : &ldsV[0][0]) + (wave & 1) * 2048;
    _Float16* dst1 = ((wave < 2) ? &ldsK[1][0] : &ldsV[1][0]) + (wave & 1) * 2048;

    #define STAGE(kt_, dd_) do {                                         \
        const _Float16* s_ = gsrc + (size_t)(kt_) * 4096;                \
        _Float16* d_ = (dd_);                                            \
        async_copy16(s_,        d_);                                     \
        async_copy16(s_ + 512,  d_ + 512);                               \
        async_copy16(s_ + 1024, d_ + 1024);                              \
        async_copy16(s_ + 1536, d_ + 1536);                              \
    } while (0)

    STAGE(0, dst0);                                  // first tile in flight

    // Q fragments (B-op: n=l31, k-slot=8h+j -> dh = t*16 + 8h + j)
    const float qscale = 1.44269504f / 64.0f;        // log2(e)/dhead folded
    half8_t qf[4];
    {
        const float* qp = Q + base + (size_t)q_abs * DH + h * 8;
        #pragma unroll
        for (int t = 0; t < 4; ++t) {
            float4 a = *(const float4*)(qp + t * 16);
            float4 b2 = *(const float4*)(qp + t * 16 + 4);
            qf[t] = (half8_t){
                (_Float16)(a.x * qscale), (_Float16)(a.y * qscale),
                (_Float16)(a.z * qscale), (_Float16)(a.w * qscale),
                (_Float16)(b2.x * qscale), (_Float16)(b2.y * qscale),
                (_Float16)(b2.z * qscale), (_Float16)(b2.w * qscale) };
        }
    }
    asm volatile("s_waitcnt vmcnt(0) lgkmcnt(0)\n\ts_barrier" ::: "memory");

    f32x16 acc0 = {}, acc1 = {};                     // O^T accumulators (d-blocks)
    float l_lane = 0.f;                              // lane-partial denom

    const _Float16* kbase = &ldsK[0][0] + lane * 8;
    const _Float16* vbase = &ldsV[0][0] + lane * 8;

    for (int kt = 0; kt < nkt; ++kt) {
        const _Float16* kk = kbase + (kt & 1) * 4096;
        const _Float16* vv = vbase + (kt & 1) * 4096;
        if (kt + 1 < nkt) STAGE(kt + 1, ((kt + 1) & 1) ? dst1 : dst0);

        // ---- S^T = K x Q^T : two 32x32 outputs (k-blocks), 8 MFMA total ----
        f32x16 st0 = {}, st1 = {};
        #pragma unroll
        for (int t = 0; t < 4; ++t) {
            half8_t kf0 = *(const half8_t*)(kk + t * 512);
            st0 = __builtin_amdgcn_mfma_f32_32x32x16_f16(kf0, qf[t], st0, 0, 0, 0);
        }
        #pragma unroll
        for (int t = 0; t < 4; ++t) {
            half8_t kf1 = *(const half8_t*)(kk + (4 + t) * 512);
            st1 = __builtin_amdgcn_mfma_f32_32x32x16_f16(kf1, qf[t], st1, 0, 0, 0);
        }

        // ---- softmax: lane owns q-row l31; reg r = k-row (r&3)+8(r>>2)+4h ----
        float p0[16], p1[16];
        #pragma unroll
        for (int r = 0; r < 16; ++r) {
            p0[r] = __builtin_amdgcn_exp2f(st0[r]);
            p1[r] = __builtin_amdgcn_exp2f(st1[r]);
        }

        if (kt >= ktdiag) {                          // diagonal tiles only
            const int kb0 = kt * 64 + h * 4;
            #pragma unroll
            for (int r = 0; r < 16; ++r) {
                const int ka = kb0 + (r & 3) + (r >> 2) * 8;
                if (ka > q_abs)      p0[r] = 0.f;
                if (ka + 32 > q_abs) p1[r] = 0.f;
            }
        }

        // lane-partial row sum (tree); cross-half reduce in epilogue
        {
            float a0 = (p0[0] + p0[1]) + (p0[2] + p0[3]);
            float a1 = (p0[4] + p0[5]) + (p0[6] + p0[7]);
            float a2 = (p0[8] + p0[9]) + (p0[10] + p0[11]);
            float a3 = (p0[12] + p0[13]) + (p0[14] + p0[15]);
            float b0 = (p1[0] + p1[1]) + (p1[2] + p1[3]);
            float b1 = (p1[4] + p1[5]) + (p1[6] + p1[7]);
            float b2 = (p1[8] + p1[9]) + (p1[10] + p1[11]);
            float b3 = (p1[12] + p1[13]) + (p1[14] + p1[15]);
            l_lane += ((a0 + a1) + (a2 + a3)) + ((b0 + b1) + (b2 + b3));
        }

        // ---- P fragments: pkrtz of consecutive registers (layout-matched) ----
        half8_t pb00 = cat8(pkrtz(p0[0], p0[1]),  pkrtz(p0[2], p0[3]),
                            pkrtz(p0[4], p0[5]),  pkrtz(p0[6], p0[7]));
        half8_t pb01 = cat8(pkrtz(p0[8], p0[9]),  pkrtz(p0[10], p0[11]),
                            pkrtz(p0[12], p0[13]), pkrtz(p0[14], p0[15]));
        half8_t pb10 = cat8(pkrtz(p1[0], p1[1]),  pkrtz(p1[2], p1[3]),
                            pkrtz(p1[4], p1[5]),  pkrtz(p1[6], p1[7]));
        half8_t pb11 = cat8(pkrtz(p1[8], p1[9]),  pkrtz(p1[10], p1[11]),
                            pkrtz(p1[12], p1[13]), pkrtz(p1[14], p1[15]));

        // ---- O^T += V^T x P^T : 2 d-blocks x 4 k-steps = 8 MFMA ----
        {
            half8_t vf0 = *(const half8_t*)(vv + 0 * 512);
            half8_t vf1 = *(const half8_t*)(vv + 1 * 512);
            half8_t vf2 = *(const half8_t*)(vv + 2 * 512);
            half8_t vf3 = *(const half8_t*)(vv + 3 * 512);
            acc0 = __builtin_amdgcn_mfma_f32_32x32x16_f16(vf0, pb00, acc0, 0, 0, 0);
            acc0 = __builtin_amdgcn_mfma_f32_32x32x16_f16(vf1, pb01, acc0, 0, 0, 0);
            acc0 = __builtin_amdgcn_mfma_f32_32x32x16_f16(vf2, pb10, acc0, 0, 0, 0);
            acc0 = __builtin_amdgcn_mfma_f32_32x32x16_f16(vf3, pb11, acc0, 0, 0, 0);
            half8_t vf4 = *(const half8_t*)(vv + 4 * 512);
            half8_t vf5 = *(const half8_t*)(vv + 5 * 512);
            half8_t vf6 = *(const half8_t*)(vv + 6 * 512);
            half8_t vf7 = *(const half8_t*)(vv + 7 * 512);
            acc1 = __builtin_amdgcn_mfma_f32_32x32x16_f16(vf4, pb00, acc1, 0, 0, 0);
            acc1 = __builtin_amdgcn_mfma_f32_32x32x16_f16(vf5, pb01, acc1, 0, 0, 0);
            acc1 = __builtin_amdgcn_mfma_f32_32x32x16_f16(vf6, pb10, acc1, 0, 0, 0);
            acc1 = __builtin_amdgcn_mfma_f32_32x32x16_f16(vf7, pb11, acc1, 0, 0, 0);
        }

        asm volatile("s_waitcnt vmcnt(0) lgkmcnt(0)\n\ts_barrier" ::: "memory");
    }

    // ---- epilogue: lane owns row q_abs; d = 32dn + 8(r>>2) + 4h + (r&3) ----
    {
        float l_i = l_lane + __shfl_xor(l_lane, 32);
        const float rl = 1.0f / l_i;
        float* op = O + base + (size_t)q_abs * DH + h * 4;
        #pragma unroll
        for (int g4 = 0; g4 < 4; ++g4) {
            float4 o0;
            o0.x = acc0[g4 * 4 + 0] * rl;
            o0.y = acc0[g4 * 4 + 1] * rl;
            o0.z = acc0[g4 * 4 + 2] * rl;
            o0.w = acc0[g4 * 4 + 3] * rl;
            *(float4*)(op + g4 * 8) = o0;
            float4 o1;
            o1.x = acc1[g4 * 4 + 0] * rl;
            o1.y = acc1[g4 * 4 + 1] * rl;
            o1.z = acc1[g4 * 4 + 2] * rl;
            o1.w = acc1[g4 * 4 + 3] * rl;
            *(float4*)(op + 32 + g4 * 8) = o1;
        }
    }
    #undef STAGE
}

extern "C" void kernel_launch(void* const* d_in, const int* in_sizes, int n_in,
                              void* d_out, int out_size, void* d_ws, size_t ws_size,
                              hipStream_t stream) {
    const float* Q = (const float*)d_in[0];
    const float* K = (const float*)d_in[1];
    const float* V = (const float*)d_in[2];
    float* O = (float*)d_out;
    _Float16* Kf = (_Float16*)d_ws;
    _Float16* Vf = Kf + (size_t)NT * 4096;           // 8 MB each
    prep_kv<<<2 * NT, 256, 0, stream>>>(K, V, Kf, Vf);
    fattn_kernel<<<16 * BHH, 256, 0, stream>>>(Q, Kf, Vf, O);
}